// Round 1
// baseline (1171.873 us; speedup 1.0000x reference)
//
#include <hip/hip_runtime.h>
#include <hip/hip_bf16.h>
#include <cstdint>
#include <cstddef>

// Problem constants (BahdanauAttention): B=32, S=2048, d=512, M=512, K=2d=1024
#define B_   32
#define S_   2048
#define D_   512
#define K2D  1024
#define M_   512

// ws layout (float indices):
//   [0,      65536)  scores  [B][S]   (zero-init, atomicAdd from GEMM epilogue)
//   [65536, 131072)  exps    [B][S]
//   [131072,131104)  denom   [B]
//   [131104,147488)  wq      [B][M]   (includes Wa_b)
//   [147488]         flag    (int: 1 => mask is packed bytes, 0 => int32)
#define WS_SCORES 0
#define WS_EXPS   65536
#define WS_DENOM  131072
#define WS_WQ     131104
#define WS_FLAG   147488

// ---------------- init: zero scores/denom/out ----------------
__global__ void k_zero(float* __restrict__ scores, float* __restrict__ denom,
                       float* __restrict__ out) {
    int tid = blockIdx.x * 256 + threadIdx.x;
    if (tid < 65536) scores[tid] = 0.f;
    else if (tid < 65568) denom[tid - 65536] = 0.f;
    if (tid < 32768) out[tid] = 0.f;
}

// ---------------- mask dtype probe ----------------
// If mask is bool bytes, first 16384 u32 words contain values >1 (packed 0/1
// bytes, ~50% true). If mask is int32 {0,1}, no word exceeds 1 anywhere.
__global__ void k_flag(const unsigned int* __restrict__ maskw, int* __restrict__ flag) {
    __shared__ int found;
    if (threadIdx.x == 0) found = 0;
    __syncthreads();
    int f = 0;
    for (int i = 0; i < 64; ++i) {
        unsigned v = maskw[threadIdx.x * 64 + i];
        if (v > 1u) f = 1;
    }
    if (f) atomicOr(&found, 1);
    __syncthreads();
    if (threadIdx.x == 0) *flag = found;
}

// ---------------- wq = query @ Wa_w^T + Wa_b ----------------
__global__ __launch_bounds__(256) void k_wq(const float* __restrict__ query,
                                            const float* __restrict__ Wa_w,
                                            const float* __restrict__ Wa_b,
                                            float* __restrict__ wq) {
    int tid = blockIdx.x * 256 + threadIdx.x;   // 0..16383
    int b = tid >> 9, m = tid & 511;
    const float4* q = (const float4*)(query + (size_t)b * D_);
    const float4* w = (const float4*)(Wa_w + (size_t)m * D_);
    float acc = 0.f;
    for (int i = 0; i < D_ / 4; ++i) {
        float4 qv = q[i], wv = w[i];
        acc = fmaf(qv.x, wv.x, acc);
        acc = fmaf(qv.y, wv.y, acc);
        acc = fmaf(qv.z, wv.z, acc);
        acc = fmaf(qv.w, wv.w, acc);
    }
    wq[tid] = acc + Wa_b[m];
}

// ---------------- fused uk-GEMM + tanh + Va reduce -> partial scores ----------
// Block tile: 128 s x 128 m, Kc=32. grid = (S/128, M/128, B).
__global__ __launch_bounds__(256) void k_scores(const float* __restrict__ keys,
                                                const float* __restrict__ Ua_w,
                                                const float* __restrict__ Ua_b,
                                                const float* __restrict__ Va_w,
                                                const float* __restrict__ wq,
                                                float* __restrict__ scores) {
    __shared__ float As[32][132];   // [k][s], +4 pad keeps 16B align & low conflicts
    __shared__ float Bs[32][132];   // [k][m]
    __shared__ float sred[128];

    const int t  = threadIdx.x;
    const int s0 = blockIdx.x * 128;
    const int m0 = blockIdx.y * 128;
    const int b  = blockIdx.z;

    const float* Ab = keys + ((size_t)b * S_ + s0) * K2D;
    const float* Bb = Ua_w + (size_t)m0 * K2D;

    const int rr = t >> 3;   // 0..31 (row within 32-row staging pass)
    const int kq = t & 7;    // 0..7  (float4 column)
    const int tx = t & 15, ty = t >> 4;

    float acc[8][8];
#pragma unroll
    for (int i = 0; i < 8; ++i)
#pragma unroll
        for (int j = 0; j < 8; ++j) acc[i][j] = 0.f;

    for (int kt = 0; kt < K2D / 32; ++kt) {
#pragma unroll
        for (int p = 0; p < 4; ++p) {
            int r = p * 32 + rr;
            float4 va = *(const float4*)(Ab + (size_t)r * K2D + kt * 32 + kq * 4);
            float4 vb = *(const float4*)(Bb + (size_t)r * K2D + kt * 32 + kq * 4);
            As[kq * 4 + 0][r] = va.x; As[kq * 4 + 1][r] = va.y;
            As[kq * 4 + 2][r] = va.z; As[kq * 4 + 3][r] = va.w;
            Bs[kq * 4 + 0][r] = vb.x; Bs[kq * 4 + 1][r] = vb.y;
            Bs[kq * 4 + 2][r] = vb.z; Bs[kq * 4 + 3][r] = vb.w;
        }
        __syncthreads();
#pragma unroll
        for (int k = 0; k < 32; ++k) {
            float4 a0 = *(const float4*)&As[k][ty * 4];
            float4 a1 = *(const float4*)&As[k][64 + ty * 4];
            float4 b0 = *(const float4*)&Bs[k][tx * 4];
            float4 b1 = *(const float4*)&Bs[k][64 + tx * 4];
            float a[8]  = {a0.x, a0.y, a0.z, a0.w, a1.x, a1.y, a1.z, a1.w};
            float bb[8] = {b0.x, b0.y, b0.z, b0.w, b1.x, b1.y, b1.z, b1.w};
#pragma unroll
            for (int i = 0; i < 8; ++i)
#pragma unroll
                for (int j = 0; j < 8; ++j)
                    acc[i][j] = fmaf(a[i], bb[j], acc[i][j]);
        }
        __syncthreads();
    }

    // epilogue: e = tanh(uk + wq + Ua_b); partial score = sum_m Va_w[m]*e
    float wqv[8], va[8];
#pragma unroll
    for (int j = 0; j < 8; ++j) {
        int ml = (j < 4) ? tx * 4 + j : 64 + tx * 4 + (j - 4);
        wqv[j] = wq[b * M_ + m0 + ml] + Ua_b[m0 + ml];
        va[j]  = Va_w[m0 + ml];
    }
    if (t < 128) sred[t] = 0.f;
    __syncthreads();
#pragma unroll
    for (int i = 0; i < 8; ++i) {
        int sl = (i < 4) ? ty * 4 + i : 64 + ty * 4 + (i - 4);
        float p = 0.f;
#pragma unroll
        for (int j = 0; j < 8; ++j)
            p += va[j] * tanhf(acc[i][j] + wqv[j]);
        atomicAdd(&sred[sl], p);
    }
    __syncthreads();
    if (t < 128) atomicAdd(&scores[(size_t)b * S_ + s0 + t], sred[t]);
}

// ---------------- masked exp + per-b denom ----------------
// No max-subtraction needed: |score| <= sum|Va_w| <= 512*0.108 = 55.5 < 88.
__global__ __launch_bounds__(256) void k_softmax(const float* __restrict__ scores,
                                                 const void* __restrict__ mask,
                                                 const int* __restrict__ flag,
                                                 float* __restrict__ exps,
                                                 float* __restrict__ denom) {
    const int b = blockIdx.x, t = threadIdx.x;
    const bool bytemode = (*flag) != 0;
    const int* mi = (const int*)mask;
    const unsigned char* mb = (const unsigned char*)mask;
    float lsum = 0.f;
#pragma unroll
    for (int i = 0; i < 8; ++i) {
        int s = i * 256 + t;
        size_t idx = (size_t)b * S_ + s;
        bool m = bytemode ? (mb[idx] != 0) : (mi[idx] != 0);
        float v = m ? 0.f : expf(scores[idx]);
        exps[idx] = v;
        lsum += v;
    }
#pragma unroll
    for (int off = 32; off > 0; off >>= 1) lsum += __shfl_down(lsum, off, 64);
    __shared__ float wsum[4];
    if ((t & 63) == 0) wsum[t >> 6] = lsum;
    __syncthreads();
    if (t == 0) denom[b] = wsum[0] + wsum[1] + wsum[2] + wsum[3];
}

// ---------------- context = (exp/denom) @ keys ----------------
// grid = (S/128, B); skips masked rows (w==0) -> ~halves keys re-read.
__global__ __launch_bounds__(256) void k_context(const float* __restrict__ keys,
                                                 const float* __restrict__ exps,
                                                 const float* __restrict__ denom,
                                                 float* __restrict__ out) {
    const int s0 = blockIdx.x * 128;
    const int b  = blockIdx.y;
    const int t  = threadIdx.x;
    const float4* kp = (const float4*)(keys + ((size_t)b * S_ + s0) * K2D);
    float4 acc = {0.f, 0.f, 0.f, 0.f};
    for (int s = 0; s < 128; ++s) {
        float w = exps[(size_t)b * S_ + s0 + s];
        if (w != 0.f) {                // uniform across block
            float4 kv = kp[(size_t)s * 256 + t];
            acc.x = fmaf(w, kv.x, acc.x);
            acc.y = fmaf(w, kv.y, acc.y);
            acc.z = fmaf(w, kv.z, acc.z);
            acc.w = fmaf(w, kv.w, acc.w);
        }
    }
    float inv = 1.0f / denom[b];
    atomicAdd(&out[b * 1024 + t * 4 + 0], acc.x * inv);
    atomicAdd(&out[b * 1024 + t * 4 + 1], acc.y * inv);
    atomicAdd(&out[b * 1024 + t * 4 + 2], acc.z * inv);
    atomicAdd(&out[b * 1024 + t * 4 + 3], acc.w * inv);
}

extern "C" void kernel_launch(void* const* d_in, const int* in_sizes, int n_in,
                              void* d_out, int out_size, void* d_ws, size_t ws_size,
                              hipStream_t stream) {
    const float* query = (const float*)d_in[0];
    const float* keys  = (const float*)d_in[1];
    const void*  mask  = d_in[2];
    const float* Wa_w  = (const float*)d_in[3];
    const float* Wa_b  = (const float*)d_in[4];
    const float* Ua_w  = (const float*)d_in[5];
    const float* Ua_b  = (const float*)d_in[6];
    const float* Va_w  = (const float*)d_in[7];
    // Va_b is softmax-invariant (constant shift on scores) -> dropped.

    float* wsf    = (float*)d_ws;
    float* scores = wsf + WS_SCORES;
    float* exps   = wsf + WS_EXPS;
    float* denom  = wsf + WS_DENOM;
    float* wq     = wsf + WS_WQ;
    int*   flag   = (int*)(wsf + WS_FLAG);
    float* out    = (float*)d_out;

    k_zero<<<257, 256, 0, stream>>>(scores, denom, out);
    k_flag<<<1, 256, 0, stream>>>((const unsigned int*)mask, flag);
    k_wq<<<64, 256, 0, stream>>>(query, Wa_w, Wa_b, wq);
    k_scores<<<dim3(S_ / 128, M_ / 128, B_), 256, 0, stream>>>(keys, Ua_w, Ua_b,
                                                               Va_w, wq, scores);
    k_softmax<<<B_, 256, 0, stream>>>(scores, mask, flag, exps, denom);
    k_context<<<dim3(S_ / 128, B_), 256, 0, stream>>>(keys, exps, denom, out);
}

// Round 2
// 570.614 us; speedup vs baseline: 2.0537x; 2.0537x over previous
//
#include <hip/hip_runtime.h>
#include <hip/hip_bf16.h>
#include <cstdint>
#include <cstddef>

// Problem constants (BahdanauAttention): B=32, S=2048, d=512, M=512, K=2d=1024
#define B_   32
#define S_   2048
#define D_   512
#define K2D  1024
#define M_   512

// ws layout (float indices) — total ~590 KB (known-safe from round 1):
#define WS_SCORES 0
#define WS_EXPS   65536
#define WS_DENOM  131072
#define WS_WQ     131104
#define WS_FLAG   147488

typedef __attribute__((ext_vector_type(8))) short bf16x8;   // 8 bf16 = 4 VGPRs
typedef __attribute__((ext_vector_type(4))) float f32x4;    // MFMA C/D frag

// tanh via exp2 pipe: tanh(x) = 1 - 2/(e^{2x}+1).  Handles +-inf correctly.
__device__ __forceinline__ float tanh_fast(float x) {
    float e = __expf(2.0f * x);
    return 1.0f - 2.0f * __builtin_amdgcn_rcpf(e + 1.0f);
}

union Pack8 { bf16x8 v; __hip_bfloat162 h[4]; };
__device__ __forceinline__ bf16x8 cvt8(float4 a, float4 b) {
    Pack8 p;
    p.h[0] = __float22bfloat162_rn(make_float2(a.x, a.y));
    p.h[1] = __float22bfloat162_rn(make_float2(a.z, a.w));
    p.h[2] = __float22bfloat162_rn(make_float2(b.x, b.y));
    p.h[3] = __float22bfloat162_rn(make_float2(b.z, b.w));
    return p.v;
}

// ---------------- init: zero scores/denom/out ----------------
__global__ void k_zero(float* __restrict__ scores, float* __restrict__ denom,
                       float* __restrict__ out) {
    int tid = blockIdx.x * 256 + threadIdx.x;
    if (tid < 65536) scores[tid] = 0.f;
    else if (tid < 65568) denom[tid - 65536] = 0.f;
    if (tid < 32768) out[tid] = 0.f;
}

// ---------------- mask dtype probe (bool-bytes vs int32) ----------------
__global__ void k_flag(const unsigned int* __restrict__ maskw, int* __restrict__ flag) {
    __shared__ int found;
    if (threadIdx.x == 0) found = 0;
    __syncthreads();
    int f = 0;
    for (int i = 0; i < 64; ++i) {
        unsigned v = maskw[threadIdx.x * 64 + i];
        if (v > 1u) f = 1;
    }
    if (f) atomicOr(&found, 1);
    __syncthreads();
    if (threadIdx.x == 0) *flag = found;
}

// ---------------- wq = query @ Wa_w^T + Wa_b ----------------
__global__ __launch_bounds__(256) void k_wq(const float* __restrict__ query,
                                            const float* __restrict__ Wa_w,
                                            const float* __restrict__ Wa_b,
                                            float* __restrict__ wq) {
    int tid = blockIdx.x * 256 + threadIdx.x;   // 0..16383
    int b = tid >> 9, m = tid & 511;
    const float4* q = (const float4*)(query + (size_t)b * D_);
    const float4* w = (const float4*)(Wa_w + (size_t)m * D_);
    float acc = 0.f;
    for (int i = 0; i < D_ / 4; ++i) {
        float4 qv = q[i], wv = w[i];
        acc = fmaf(qv.x, wv.x, acc);
        acc = fmaf(qv.y, wv.y, acc);
        acc = fmaf(qv.z, wv.z, acc);
        acc = fmaf(qv.w, wv.w, acc);
    }
    wq[tid] = acc + Wa_b[m];
}

// ---------------- MFMA scores: uk-GEMM(bf16) + tanh + Va reduce ----------
// C[s,m] = sum_k keys[b,s,k]*Ua_w[m,k]; both operands K-major (B^T GEMM).
// Block tile 128s x 128m, BK=64, 4 waves in 2x2, each wave 4x4 16x16x32 tiles.
// grid = (M/128=4, S/128=16, B) — m fastest so the 4 m-blocks sharing a keys
// s-chunk run adjacently (LLC absorbs the 4x re-read of fp32 keys).
__global__ __launch_bounds__(256, 2) void k_scores(const float* __restrict__ keys,
                                                   const float* __restrict__ Ua_w,
                                                   const float* __restrict__ Ua_b,
                                                   const float* __restrict__ Va_w,
                                                   const float* __restrict__ wq,
                                                   float* __restrict__ scores) {
    __shared__ ushort As[128 * 72];   // [row][72] (64 k + 8 pad), 144B rows, 16B-aligned
    __shared__ ushort Bs[128 * 72];

    const int t  = threadIdx.x;
    const int m0 = blockIdx.x * 128;
    const int s0 = blockIdx.y * 128;
    const int b  = blockIdx.z;
    const int wave = t >> 6, lane = t & 63;
    const int q = lane >> 4, r = lane & 15;
    const int sw = (wave >> 1) * 64, mw = (wave & 1) * 64;
    const int rb = t >> 3;     // staging row base 0..31
    const int kq = t & 7;      // staging k-chunk (8 floats)

    const float* Ab = keys + ((size_t)b * S_ + s0 + rb) * K2D + kq * 8;
    const float* Bb = Ua_w + ((size_t)(m0 + rb)) * K2D + kq * 8;
    ushort* aw = &As[rb * 72 + kq * 8];
    ushort* bw = &Bs[rb * 72 + kq * 8];

    f32x4 acc[4][4];
#pragma unroll
    for (int i = 0; i < 4; ++i)
#pragma unroll
        for (int j = 0; j < 4; ++j) acc[i][j] = (f32x4){0.f, 0.f, 0.f, 0.f};

    for (int kt = 0; kt < K2D / 64; ++kt) {
        const int ko = kt * 64;
#pragma unroll
        for (int p = 0; p < 4; ++p) {
            const float* sa = Ab + (size_t)(p * 32) * K2D + ko;
            float4 a0 = *(const float4*)sa;
            float4 a1 = *(const float4*)(sa + 4);
            *(bf16x8*)(aw + p * 32 * 72) = cvt8(a0, a1);
            const float* sb = Bb + (size_t)(p * 32) * K2D + ko;
            float4 b0 = *(const float4*)sb;
            float4 b1 = *(const float4*)(sb + 4);
            *(bf16x8*)(bw + p * 32 * 72) = cvt8(b0, b1);
        }
        __syncthreads();
#pragma unroll
        for (int ks = 0; ks < 2; ++ks) {
            bf16x8 af[4], bfr[4];
#pragma unroll
            for (int i = 0; i < 4; ++i)
                af[i] = *(const bf16x8*)&As[(sw + i * 16 + r) * 72 + ks * 32 + q * 8];
#pragma unroll
            for (int j = 0; j < 4; ++j)
                bfr[j] = *(const bf16x8*)&Bs[(mw + j * 16 + r) * 72 + ks * 32 + q * 8];
#pragma unroll
            for (int i = 0; i < 4; ++i)
#pragma unroll
                for (int j = 0; j < 4; ++j)
                    acc[i][j] = __builtin_amdgcn_mfma_f32_16x16x32_bf16(
                        af[i], bfr[j], acc[i][j], 0, 0, 0);
        }
        __syncthreads();
    }

    // Epilogue. C/D layout: col(m) = lane&15, row(s) = q*4+reg.
    float vaw[4], wqb[4];
#pragma unroll
    for (int j = 0; j < 4; ++j) {
        int m = m0 + mw + 16 * j + r;
        vaw[j] = Va_w[m];
        wqb[j] = wq[b * M_ + m] + Ua_b[m];
    }
    float* red = (float*)As;           // overlay: 128 x 33 floats = 16.9 KB < 18 KB
    const int col = (wave & 1) * 16 + r;
#pragma unroll
    for (int i = 0; i < 4; ++i) {
#pragma unroll
        for (int rg = 0; rg < 4; ++rg) {
            int sl = sw + 16 * i + 4 * q + rg;
            float p = 0.f;
#pragma unroll
            for (int j = 0; j < 4; ++j)
                p += vaw[j] * tanh_fast(acc[i][j][rg] + wqb[j]);
            red[sl * 33 + col] = p;    // every (sl,col) written exactly once
        }
    }
    __syncthreads();
    if (t < 128) {
        float sum = 0.f;
#pragma unroll
        for (int c = 0; c < 32; ++c) sum += red[t * 33 + c];
        atomicAdd(&scores[(size_t)b * S_ + s0 + t], sum);
    }
}

// ---------------- masked exp + per-b denom ----------------
// |score| <= sum|Va_w| ~ 55.5 < 88, so no max-subtraction needed.
__global__ __launch_bounds__(256) void k_softmax(const float* __restrict__ scores,
                                                 const void* __restrict__ mask,
                                                 const int* __restrict__ flag,
                                                 float* __restrict__ exps,
                                                 float* __restrict__ denom) {
    const int b = blockIdx.x, t = threadIdx.x;
    const bool bytemode = (*flag) != 0;
    const int* mi = (const int*)mask;
    const unsigned char* mb = (const unsigned char*)mask;
    float lsum = 0.f;
#pragma unroll
    for (int i = 0; i < 8; ++i) {
        int s = i * 256 + t;
        size_t idx = (size_t)b * S_ + s;
        bool m = bytemode ? (mb[idx] != 0) : (mi[idx] != 0);
        float v = m ? 0.f : expf(scores[idx]);
        exps[idx] = v;
        lsum += v;
    }
#pragma unroll
    for (int off = 32; off > 0; off >>= 1) lsum += __shfl_down(lsum, off, 64);
    __shared__ float wsum[4];
    if ((t & 63) == 0) wsum[t >> 6] = lsum;
    __syncthreads();
    if (t == 0) denom[b] = wsum[0] + wsum[1] + wsum[2] + wsum[3];
}

// ---------------- context = (exp/denom) @ keys ----------------
// 64 s-rows per block -> 1024 blocks; branchless (w=0 contributes 0) so the
// compiler can fully pipeline the 64 independent float4 loads.
__global__ __launch_bounds__(256) void k_context(const float* __restrict__ keys,
                                                 const float* __restrict__ exps,
                                                 const float* __restrict__ denom,
                                                 float* __restrict__ out) {
    __shared__ float w[64];
    const int s0 = blockIdx.x * 64;
    const int b  = blockIdx.y;
    const int t  = threadIdx.x;
    if (t < 64) w[t] = exps[(size_t)b * S_ + s0 + t];
    __syncthreads();
    const float4* kp = (const float4*)(keys + ((size_t)b * S_ + s0) * K2D);
    float4 acc = {0.f, 0.f, 0.f, 0.f};
#pragma unroll 8
    for (int s = 0; s < 64; ++s) {
        float ws = w[s];
        float4 kv = kp[(size_t)s * 256 + t];
        acc.x = fmaf(ws, kv.x, acc.x);
        acc.y = fmaf(ws, kv.y, acc.y);
        acc.z = fmaf(ws, kv.z, acc.z);
        acc.w = fmaf(ws, kv.w, acc.w);
    }
    float inv = 1.0f / denom[b];
    atomicAdd(&out[b * 1024 + t * 4 + 0], acc.x * inv);
    atomicAdd(&out[b * 1024 + t * 4 + 1], acc.y * inv);
    atomicAdd(&out[b * 1024 + t * 4 + 2], acc.z * inv);
    atomicAdd(&out[b * 1024 + t * 4 + 3], acc.w * inv);
}

extern "C" void kernel_launch(void* const* d_in, const int* in_sizes, int n_in,
                              void* d_out, int out_size, void* d_ws, size_t ws_size,
                              hipStream_t stream) {
    const float* query = (const float*)d_in[0];
    const float* keys  = (const float*)d_in[1];
    const void*  mask  = d_in[2];
    const float* Wa_w  = (const float*)d_in[3];
    const float* Wa_b  = (const float*)d_in[4];
    const float* Ua_w  = (const float*)d_in[5];
    const float* Ua_b  = (const float*)d_in[6];
    const float* Va_w  = (const float*)d_in[7];
    // Va_b is softmax-invariant -> dropped.

    float* wsf    = (float*)d_ws;
    float* scores = wsf + WS_SCORES;
    float* exps   = wsf + WS_EXPS;
    float* denom  = wsf + WS_DENOM;
    float* wq     = wsf + WS_WQ;
    int*   flag   = (int*)(wsf + WS_FLAG);
    float* out    = (float*)d_out;

    k_zero<<<257, 256, 0, stream>>>(scores, denom, out);
    k_flag<<<1, 256, 0, stream>>>((const unsigned int*)mask, flag);
    k_wq<<<64, 256, 0, stream>>>(query, Wa_w, Wa_b, wq);
    k_scores<<<dim3(M_ / 128, S_ / 128, B_), 256, 0, stream>>>(keys, Ua_w, Ua_b,
                                                               Va_w, wq, scores);
    k_softmax<<<B_, 256, 0, stream>>>(scores, mask, flag, exps, denom);
    k_context<<<dim3(S_ / 64, B_), 256, 0, stream>>>(keys, exps, denom, out);
}